// Round 12
// baseline (107.194 us; speedup 1.0000x reference)
//
#include <hip/hip_runtime.h>

// STAttn v11 "wave-streaming x2": B,T,N,D=32,32,64,512; H=64; OUT=256.
// R11 post-mortem: latency-bound at 2 waves/SIMD (occ 20.8%), VGPR=44.
// Fixes: (a) 4 waves/bt (nh,jh 32x32 tiles) -> 4096 waves = 4/SIMD;
//        (b) ue_w pre-split ONCE to bf16 hi/lo in d_ws (kernel 0) ->
//            B-operands are direct 16B bf16x8 loads, no per-wave B-split.
// Kernel 1: zero-barrier k-loop, direct global->fragment; 2 block barriers
//           (e-exchange, a-publish); pooling = streamed L3-hot pass.
// Kernel 2 (fc2): attr @ fc1_w^T + b (proven R6).
// Fallbacks: PRE=0 (ws < 2MB+128KB) splits B in-kernel; MODE=1 (ws < 2MB)
//            fuses fc in-block.

typedef __attribute__((ext_vector_type(8)))  short bf16x8;
typedef __attribute__((ext_vector_type(16))) float f32x16;

// one float -> bf16 hi (trunc) + lo (residual, trunc); alo*blo (~2^-16) dropped
#define SPL(f, i) do {                                                        \
    const unsigned u_ = __float_as_uint(f);                                   \
    h8[i] = (short)(u_ >> 16);                                                \
    const float hf_ = __uint_as_float(u_ & 0xFFFF0000u);                      \
    l8[i] = (short)(__float_as_uint((f) - hf_) >> 16);                        \
} while (0)

__device__ __forceinline__ void split8v(float4 va, float4 vb,
                                        bf16x8& h8, bf16x8& l8) {
    SPL(va.x, 0); SPL(va.y, 1); SPL(va.z, 2); SPL(va.w, 3);
    SPL(vb.x, 4); SPL(vb.y, 5); SPL(vb.z, 6); SPL(vb.w, 7);
}

// kernel 0: split ue_w (64x512 fp32) -> hi/lo bf16 planes in d_ws
__global__ __launch_bounds__(256) void presplit_ue(
    const float* __restrict__ w, unsigned short* __restrict__ hi,
    unsigned short* __restrict__ lo)
{
    const int i4 = (blockIdx.x * 256 + threadIdx.x) * 4;   // grid 32 -> 32768
    const float4 v = *reinterpret_cast<const float4*>(&w[i4]);
    ushort4 h, l;
    {
        unsigned u;
        u = __float_as_uint(v.x); h.x = (unsigned short)(u >> 16);
        l.x = (unsigned short)(__float_as_uint(v.x - __uint_as_float(u & 0xFFFF0000u)) >> 16);
        u = __float_as_uint(v.y); h.y = (unsigned short)(u >> 16);
        l.y = (unsigned short)(__float_as_uint(v.y - __uint_as_float(u & 0xFFFF0000u)) >> 16);
        u = __float_as_uint(v.z); h.z = (unsigned short)(u >> 16);
        l.z = (unsigned short)(__float_as_uint(v.z - __uint_as_float(u & 0xFFFF0000u)) >> 16);
        u = __float_as_uint(v.w); h.w = (unsigned short)(u >> 16);
        l.w = (unsigned short)(__float_as_uint(v.w - __uint_as_float(u & 0xFFFF0000u)) >> 16);
    }
    *reinterpret_cast<ushort4*>(&hi[i4]) = h;
    *reinterpret_cast<ushort4*>(&lo[i4]) = l;
}

template<int MODE, int PRE>
__global__ __launch_bounds__(256, 4) void stattn_ea(
    const float* __restrict__ inp,            // [1024][64][512]
    const float* __restrict__ ue_w,           // [64][512] (PRE=0)
    const unsigned short* __restrict__ ue_hi, // [64][512] bf16 (PRE=1)
    const unsigned short* __restrict__ ue_lo, // [64][512] bf16 (PRE=1)
    const float* __restrict__ ue_b,           // [64]
    const float* __restrict__ be,             // [64]
    const float* __restrict__ w_w,            // [64]
    const float* __restrict__ fc1_w,          // [256][512] (MODE 1 only)
    const float* __restrict__ fc1_b,          // [256]      (MODE 1 only)
    float* __restrict__ dst)                  // MODE 0: attr; MODE 1: out
{
    __shared__ float ep_s[2][64];
    __shared__ float a_s[64];
    __shared__ __align__(16) float attr_s[512];  // MODE 1 only

    const int tid = threadIdx.x;
    const int wv  = tid >> 6;
    const int l   = tid & 63;
    const int l31 = l & 31;
    const int hi5 = l >> 5;
    const int nh  = wv >> 1;        // token half
    const int jh  = wv & 1;         // hidden half
    const int bt  = blockIdx.x;
    const float* __restrict__ xg = inp + (size_t)bt * (64 * 512);

    // ---- phase 1: 32x32 h-tile per wave, K=512, zero barriers ----
    const float* __restrict__ arow = xg + (nh * 32 + l31) * 512 + hi5 * 8;
    const int brow = jh * 32 + l31;

    f32x16 acc = {};
    if (PRE) {
        const unsigned short* __restrict__ bhp = ue_hi + brow * 512 + hi5 * 8;
        const unsigned short* __restrict__ blp = ue_lo + brow * 512 + hi5 * 8;
#pragma unroll 4
        for (int ks = 0; ks < 32; ++ks) {
            const int k = ks * 16;
            const float4 a0 = *reinterpret_cast<const float4*>(&arow[k]);
            const float4 a1 = *reinterpret_cast<const float4*>(&arow[k + 4]);
            const bf16x8 bh = *reinterpret_cast<const bf16x8*>(&bhp[k]);
            const bf16x8 bl = *reinterpret_cast<const bf16x8*>(&blp[k]);
            bf16x8 h8, l8;
            split8v(a0, a1, h8, l8);
            acc = __builtin_amdgcn_mfma_f32_32x32x16_bf16(h8, bh, acc, 0, 0, 0);
            acc = __builtin_amdgcn_mfma_f32_32x32x16_bf16(l8, bh, acc, 0, 0, 0);
            acc = __builtin_amdgcn_mfma_f32_32x32x16_bf16(h8, bl, acc, 0, 0, 0);
        }
    } else {
        const float* __restrict__ bp = ue_w + brow * 512 + hi5 * 8;
#pragma unroll 4
        for (int ks = 0; ks < 32; ++ks) {
            const int k = ks * 16;
            const float4 a0 = *reinterpret_cast<const float4*>(&arow[k]);
            const float4 a1 = *reinterpret_cast<const float4*>(&arow[k + 4]);
            const float4 b0 = *reinterpret_cast<const float4*>(&bp[k]);
            const float4 b1 = *reinterpret_cast<const float4*>(&bp[k + 4]);
            bf16x8 ah, al, bh, bl;
            { bf16x8 &h8 = ah, &l8 = al; split8v(a0, a1, h8, l8); }
            { bf16x8 &h8 = bh, &l8 = bl; split8v(b0, b1, h8, l8); }
            acc = __builtin_amdgcn_mfma_f32_32x32x16_bf16(ah, bh, acc, 0, 0, 0);
            acc = __builtin_amdgcn_mfma_f32_32x32x16_bf16(al, bh, acc, 0, 0, 0);
            acc = __builtin_amdgcn_mfma_f32_32x32x16_bf16(ah, bl, acc, 0, 0, 0);
        }
    }

    // ---- phase 2: e = lrelu(h+bias)@w_w (w_b dropped: softmax shift-inv) ----
    // C/D layout (m74/m101): col j = l&31, row n = (r&3) + 8*(r>>2) + 4*(l>>5)
    {
        const int j = jh * 32 + l31;
        const float bias = ue_b[j] + be[j];
        const float ww   = w_w[j];
#pragma unroll
        for (int r = 0; r < 16; ++r) {
            float hv = acc[r] + bias;
            hv = hv > 0.f ? hv : 0.2f * hv;
            float p = hv * ww;
            p += __shfl_xor(p, 1);
            p += __shfl_xor(p, 2);
            p += __shfl_xor(p, 4);
            p += __shfl_xor(p, 8);
            p += __shfl_xor(p, 16);
            if (l31 == 0)
                ep_s[jh][nh * 32 + (r & 3) + 8 * (r >> 2) + 4 * hi5] = p;
        }
    }
    __syncthreads();

    // ---- softmax over 64 tokens (wave 0 computes & publishes) ----
    if (wv == 0) {
        const float v = ep_s[0][l] + ep_s[1][l];
        float mx = v;
#pragma unroll
        for (int off = 32; off >= 1; off >>= 1) mx = fmaxf(mx, __shfl_xor(mx, off));
        const float ex = expf(v - mx);
        float sm = ex;
#pragma unroll
        for (int off = 32; off >= 1; off >>= 1) sm += __shfl_xor(sm, off);
        a_s[l] = ex / sm;
    }
    __syncthreads();

    // ---- phase 3: pooling, streamed L2/L3-hot pass, no barriers ----
    {
        const int d0 = tid * 2;
        const float* __restrict__ xp = xg + d0;
        float sx = 0.f, sy = 0.f;
#pragma unroll 8
        for (int n = 0; n < 64; ++n) {
            const float an  = a_s[n];
            const float2 xv = *reinterpret_cast<const float2*>(&xp[n * 512]);
            sx = fmaf(an, xv.x, sx);
            sy = fmaf(an, xv.y, sy);
        }
        if (MODE == 0) {
            float2 o; o.x = sx; o.y = sy;
            *reinterpret_cast<float2*>(&dst[(size_t)bt * 512 + d0]) = o;
        } else {
            attr_s[d0]     = sx;
            attr_s[d0 + 1] = sy;
        }
    }

    if (MODE == 1) {
        __syncthreads();
        const int o = tid;
        const float* __restrict__ wr = fc1_w + o * 512;
        float s0 = 0.f, s1 = 0.f, s2 = 0.f, s3 = 0.f;
#pragma unroll 8
        for (int i = 0; i < 128; ++i) {
            const float4 w4 = *reinterpret_cast<const float4*>(&wr[i * 4]);
            const float4 a4 = *reinterpret_cast<const float4*>(&attr_s[i * 4]);
            s0 = fmaf(a4.x, w4.x, s0);
            s1 = fmaf(a4.y, w4.y, s1);
            s2 = fmaf(a4.z, w4.z, s2);
            s3 = fmaf(a4.w, w4.w, s3);
        }
        const int row = (bt & 31) * 32 + (bt >> 5);
        dst[row * 256 + o] = (s0 + s1) + (s2 + s3) + fc1_b[o];
    }
}

// fc GEMM: out[(bt&31)*32+(bt>>5)][o] = attr[bt] . fc1_w[o] + fc1_b[o]
__global__ __launch_bounds__(256, 2) void stattn_fc2(
    const float* __restrict__ attr,   // [1024][512] (d_ws)
    const float* __restrict__ fc1_w,  // [256][512]
    const float* __restrict__ fc1_b,  // [256]
    float* __restrict__ out)          // [1024][256]
{
    __shared__ __align__(16) float at[32][516];
    const int tid = threadIdx.x;
    const int bm  = blockIdx.x;
    const int bn  = blockIdx.y;

    {
        const int row = tid >> 3;
        const int seg = tid & 7;
        const float* __restrict__ src = attr + (size_t)(bm * 32 + row) * 512 + seg * 64;
#pragma unroll
        for (int q = 0; q < 16; ++q)
            *reinterpret_cast<float4*>(&at[row][seg * 64 + q * 4]) =
                *reinterpret_cast<const float4*>(&src[q * 4]);
    }
    __syncthreads();

    const int tx = tid & 31;
    const int ty = tid >> 5;
    const int o  = bn * 32 + tx;
    const float* __restrict__ wr = fc1_w + (size_t)o * 512;
    float s0 = 0.f, s1 = 0.f, s2 = 0.f, s3 = 0.f;
#pragma unroll 4
    for (int kq = 0; kq < 128; ++kq) {
        const float4 w4 = *reinterpret_cast<const float4*>(&wr[kq * 4]);
        const float4 a0 = *reinterpret_cast<const float4*>(&at[ty * 4 + 0][kq * 4]);
        const float4 a1 = *reinterpret_cast<const float4*>(&at[ty * 4 + 1][kq * 4]);
        const float4 a2 = *reinterpret_cast<const float4*>(&at[ty * 4 + 2][kq * 4]);
        const float4 a3 = *reinterpret_cast<const float4*>(&at[ty * 4 + 3][kq * 4]);
        s0 += a0.x * w4.x + a0.y * w4.y + a0.z * w4.z + a0.w * w4.w;
        s1 += a1.x * w4.x + a1.y * w4.y + a1.z * w4.z + a1.w * w4.w;
        s2 += a2.x * w4.x + a2.y * w4.y + a2.z * w4.z + a2.w * w4.w;
        s3 += a3.x * w4.x + a3.y * w4.y + a3.z * w4.z + a3.w * w4.w;
    }
    const float fb = fc1_b[o];
    float sv0 = s0 + fb, sv1 = s1 + fb, sv2 = s2 + fb, sv3 = s3 + fb;
    {
        int btv = bm * 32 + ty * 4;
        out[((btv & 31) * 32 + (btv >> 5)) * 256 + o] = sv0; ++btv;
        out[((btv & 31) * 32 + (btv >> 5)) * 256 + o] = sv1; ++btv;
        out[((btv & 31) * 32 + (btv >> 5)) * 256 + o] = sv2; ++btv;
        out[((btv & 31) * 32 + (btv >> 5)) * 256 + o] = sv3;
    }
}

extern "C" void kernel_launch(void* const* d_in, const int* in_sizes, int n_in,
                              void* d_out, int out_size, void* d_ws, size_t ws_size,
                              hipStream_t stream) {
    const float* inp   = (const float*)d_in[0];
    const float* ue_w  = (const float*)d_in[1];
    const float* ue_b  = (const float*)d_in[2];
    const float* be    = (const float*)d_in[3];
    const float* w_w   = (const float*)d_in[4];
    // d_in[5] = w_b: unused (softmax invariant to constant shift)
    const float* fc1_w = (const float*)d_in[6];
    const float* fc1_b = (const float*)d_in[7];
    float* out = (float*)d_out;

    const size_t ATTR_BYTES = (size_t)1024 * 512 * 4;           // 2 MB
    const size_t PRE_BYTES  = (size_t)64 * 512 * 2 * 2;         // 128 KB
    const bool split = ws_size >= ATTR_BYTES;                   // confirmed R6
    const bool pre   = ws_size >= ATTR_BYTES + PRE_BYTES;

    if (split) {
        float* attr = (float*)d_ws;
        unsigned short* ue_hi =
            (unsigned short*)((char*)d_ws + ATTR_BYTES);
        unsigned short* ue_lo = ue_hi + 64 * 512;
        if (pre) {
            presplit_ue<<<32, 256, 0, stream>>>(ue_w, ue_hi, ue_lo);
            stattn_ea<0, 1><<<1024, 256, 0, stream>>>(
                inp, ue_w, ue_hi, ue_lo, ue_b, be, w_w, fc1_w, fc1_b, attr);
        } else {
            stattn_ea<0, 0><<<1024, 256, 0, stream>>>(
                inp, ue_w, ue_hi, ue_lo, ue_b, be, w_w, fc1_w, fc1_b, attr);
        }
        stattn_fc2<<<dim3(32, 8), 256, 0, stream>>>(attr, fc1_w, fc1_b, out);
    } else {
        stattn_ea<1, 0><<<1024, 256, 0, stream>>>(
            inp, ue_w, nullptr, nullptr, ue_b, be, w_w, fc1_w, fc1_b, out);
    }
}

// Round 13
// 103.301 us; speedup vs baseline: 1.0377x; 1.0377x over previous
//
#include <hip/hip_runtime.h>

// STAttn v12 "manual pipeline": B,T,N,D=32,32,64,512; H=64; OUT=256.
// R12 post-mortem: VGPR=32 -> compiler schedules loads just-before-use,
// zero pipelining, ~8000cy per k-step. Fix: explicit 4-slot software
// pipeline with NAMED variables (no arrays -> no scratch, rule #20),
// reload-after-consume so ~3 k-steps of loads stay in flight per wave.
// Skeleton unchanged from R12: 1024 blocks x 4 waves (nh,jh), pre-split
// ue_w (bf16 hi/lo in d_ws), zero-barrier k-loop, 2 block barriers,
// streamed pooling; fc2 kernel for the fc GEMM.

typedef __attribute__((ext_vector_type(8)))  short bf16x8;
typedef __attribute__((ext_vector_type(16))) float f32x16;

#define SCHEDB() __builtin_amdgcn_sched_barrier(0)

// one float -> bf16 hi (trunc) + lo (residual, trunc); alo*blo (~2^-16) dropped
#define SPL(f, i) do {                                                        \
    const unsigned u_ = __float_as_uint(f);                                   \
    h8[i] = (short)(u_ >> 16);                                                \
    const float hf_ = __uint_as_float(u_ & 0xFFFF0000u);                      \
    l8[i] = (short)(__float_as_uint((f) - hf_) >> 16);                        \
} while (0)

__device__ __forceinline__ void split8v(float4 va, float4 vb,
                                        bf16x8& h8, bf16x8& l8) {
    SPL(va.x, 0); SPL(va.y, 1); SPL(va.z, 2); SPL(va.w, 3);
    SPL(vb.x, 4); SPL(vb.y, 5); SPL(vb.z, 6); SPL(vb.w, 7);
}

// kernel 0: split ue_w (64x512 fp32) -> hi/lo bf16 planes in d_ws
__global__ __launch_bounds__(256) void presplit_ue(
    const float* __restrict__ w, unsigned short* __restrict__ hi,
    unsigned short* __restrict__ lo)
{
    const int i4 = (blockIdx.x * 256 + threadIdx.x) * 4;   // grid 32 -> 32768
    const float4 v = *reinterpret_cast<const float4*>(&w[i4]);
    ushort4 h, l;
    {
        unsigned u;
        u = __float_as_uint(v.x); h.x = (unsigned short)(u >> 16);
        l.x = (unsigned short)(__float_as_uint(v.x - __uint_as_float(u & 0xFFFF0000u)) >> 16);
        u = __float_as_uint(v.y); h.y = (unsigned short)(u >> 16);
        l.y = (unsigned short)(__float_as_uint(v.y - __uint_as_float(u & 0xFFFF0000u)) >> 16);
        u = __float_as_uint(v.z); h.z = (unsigned short)(u >> 16);
        l.z = (unsigned short)(__float_as_uint(v.z - __uint_as_float(u & 0xFFFF0000u)) >> 16);
        u = __float_as_uint(v.w); h.w = (unsigned short)(u >> 16);
        l.w = (unsigned short)(__float_as_uint(v.w - __uint_as_float(u & 0xFFFF0000u)) >> 16);
    }
    *reinterpret_cast<ushort4*>(&hi[i4]) = h;
    *reinterpret_cast<ushort4*>(&lo[i4]) = l;
}

template<int MODE, int PRE>
__global__ __launch_bounds__(256, 2) void stattn_ea(
    const float* __restrict__ inp,            // [1024][64][512]
    const float* __restrict__ ue_w,           // [64][512] (PRE=0)
    const unsigned short* __restrict__ ue_hi, // [64][512] bf16 (PRE=1)
    const unsigned short* __restrict__ ue_lo, // [64][512] bf16 (PRE=1)
    const float* __restrict__ ue_b,           // [64]
    const float* __restrict__ be,             // [64]
    const float* __restrict__ w_w,            // [64]
    const float* __restrict__ fc1_w,          // [256][512] (MODE 1 only)
    const float* __restrict__ fc1_b,          // [256]      (MODE 1 only)
    float* __restrict__ dst)                  // MODE 0: attr; MODE 1: out
{
    __shared__ float ep_s[2][64];
    __shared__ float a_s[64];
    __shared__ __align__(16) float attr_s[512];  // MODE 1 only

    const int tid = threadIdx.x;
    const int wv  = tid >> 6;
    const int l   = tid & 63;
    const int l31 = l & 31;
    const int hi5 = l >> 5;
    const int nh  = wv >> 1;        // token half
    const int jh  = wv & 1;         // hidden half
    const int bt  = blockIdx.x;
    const float* __restrict__ xg = inp + (size_t)bt * (64 * 512);

    // ---- phase 1: 32x32 h-tile per wave, K=512, zero barriers,
    //      explicit 4-slot load pipeline (named vars only) ----
    const float* __restrict__ arow = xg + (nh * 32 + l31) * 512 + hi5 * 8;
    const int brow = jh * 32 + l31;

    f32x16 acc = {};

    if (PRE) {
        const unsigned short* __restrict__ bhp = ue_hi + brow * 512 + hi5 * 8;
        const unsigned short* __restrict__ blp = ue_lo + brow * 512 + hi5 * 8;

        float4 xa0, xb0, xa1, xb1, xa2, xb2, xa3, xb3;
        bf16x8 bh0, bl0, bh1, bl1, bh2, bl2, bh3, bl3;

#define LOADS(i, ks) do {                                                     \
    xa##i = *reinterpret_cast<const float4*>(&arow[(ks) * 16]);               \
    xb##i = *reinterpret_cast<const float4*>(&arow[(ks) * 16 + 4]);           \
    bh##i = *reinterpret_cast<const bf16x8*>(&bhp[(ks) * 16]);                \
    bl##i = *reinterpret_cast<const bf16x8*>(&blp[(ks) * 16]);                \
} while (0)
#define COMPS(i) do {                                                         \
    bf16x8 h8, l8;                                                            \
    split8v(xa##i, xb##i, h8, l8);                                            \
    acc = __builtin_amdgcn_mfma_f32_32x32x16_bf16(h8, bh##i, acc, 0, 0, 0);   \
    acc = __builtin_amdgcn_mfma_f32_32x32x16_bf16(l8, bh##i, acc, 0, 0, 0);   \
    acc = __builtin_amdgcn_mfma_f32_32x32x16_bf16(h8, bl##i, acc, 0, 0, 0);   \
} while (0)

        LOADS(0, 0); LOADS(1, 1); LOADS(2, 2); LOADS(3, 3);
        SCHEDB();
#pragma unroll
        for (int ks = 0; ks < 32; ks += 4) {
            COMPS(0); if (ks + 4 < 32) LOADS(0, ks + 4); SCHEDB();
            COMPS(1); if (ks + 5 < 32) LOADS(1, ks + 5); SCHEDB();
            COMPS(2); if (ks + 6 < 32) LOADS(2, ks + 6); SCHEDB();
            COMPS(3); if (ks + 7 < 32) LOADS(3, ks + 7); SCHEDB();
        }
#undef LOADS
#undef COMPS
    } else {
        const float* __restrict__ bp = ue_w + brow * 512 + hi5 * 8;
#pragma unroll 4
        for (int ks = 0; ks < 32; ++ks) {
            const int k = ks * 16;
            const float4 a0 = *reinterpret_cast<const float4*>(&arow[k]);
            const float4 a1 = *reinterpret_cast<const float4*>(&arow[k + 4]);
            const float4 b0 = *reinterpret_cast<const float4*>(&bp[k]);
            const float4 b1 = *reinterpret_cast<const float4*>(&bp[k + 4]);
            bf16x8 ah, al, bh, bl;
            { bf16x8 &h8 = ah, &l8 = al; split8v(a0, a1, h8, l8); }
            { bf16x8 &h8 = bh, &l8 = bl; split8v(b0, b1, h8, l8); }
            acc = __builtin_amdgcn_mfma_f32_32x32x16_bf16(ah, bh, acc, 0, 0, 0);
            acc = __builtin_amdgcn_mfma_f32_32x32x16_bf16(al, bh, acc, 0, 0, 0);
            acc = __builtin_amdgcn_mfma_f32_32x32x16_bf16(ah, bl, acc, 0, 0, 0);
        }
    }

    // ---- phase 2: e = lrelu(h+bias)@w_w (w_b dropped: softmax shift-inv) ----
    // C/D layout (m74/m101): col j = l&31, row n = (r&3) + 8*(r>>2) + 4*(l>>5)
    {
        const int j = jh * 32 + l31;
        const float bias = ue_b[j] + be[j];
        const float ww   = w_w[j];
#pragma unroll
        for (int r = 0; r < 16; ++r) {
            float hv = acc[r] + bias;
            hv = hv > 0.f ? hv : 0.2f * hv;
            float p = hv * ww;
            p += __shfl_xor(p, 1);
            p += __shfl_xor(p, 2);
            p += __shfl_xor(p, 4);
            p += __shfl_xor(p, 8);
            p += __shfl_xor(p, 16);
            if (l31 == 0)
                ep_s[jh][nh * 32 + (r & 3) + 8 * (r >> 2) + 4 * hi5] = p;
        }
    }
    __syncthreads();

    // ---- softmax over 64 tokens (wave 0 computes & publishes) ----
    if (wv == 0) {
        const float v = ep_s[0][l] + ep_s[1][l];
        float mx = v;
#pragma unroll
        for (int off = 32; off >= 1; off >>= 1) mx = fmaxf(mx, __shfl_xor(mx, off));
        const float ex = expf(v - mx);
        float sm = ex;
#pragma unroll
        for (int off = 32; off >= 1; off >>= 1) sm += __shfl_xor(sm, off);
        a_s[l] = ex / sm;
    }
    __syncthreads();

    // ---- phase 3: pooling, streamed L2/L3-hot pass, no barriers ----
    {
        const int d0 = tid * 2;
        const float* __restrict__ xp = xg + d0;
        float sx = 0.f, sy = 0.f;
#pragma unroll 8
        for (int n = 0; n < 64; ++n) {
            const float an  = a_s[n];
            const float2 xv = *reinterpret_cast<const float2*>(&xp[n * 512]);
            sx = fmaf(an, xv.x, sx);
            sy = fmaf(an, xv.y, sy);
        }
        if (MODE == 0) {
            float2 o; o.x = sx; o.y = sy;
            *reinterpret_cast<float2*>(&dst[(size_t)bt * 512 + d0]) = o;
        } else {
            attr_s[d0]     = sx;
            attr_s[d0 + 1] = sy;
        }
    }

    if (MODE == 1) {
        __syncthreads();
        const int o = tid;
        const float* __restrict__ wr = fc1_w + o * 512;
        float s0 = 0.f, s1 = 0.f, s2 = 0.f, s3 = 0.f;
#pragma unroll 8
        for (int i = 0; i < 128; ++i) {
            const float4 w4 = *reinterpret_cast<const float4*>(&wr[i * 4]);
            const float4 a4 = *reinterpret_cast<const float4*>(&attr_s[i * 4]);
            s0 = fmaf(a4.x, w4.x, s0);
            s1 = fmaf(a4.y, w4.y, s1);
            s2 = fmaf(a4.z, w4.z, s2);
            s3 = fmaf(a4.w, w4.w, s3);
        }
        const int row = (bt & 31) * 32 + (bt >> 5);
        dst[row * 256 + o] = (s0 + s1) + (s2 + s3) + fc1_b[o];
    }
}

// fc GEMM: out[(bt&31)*32+(bt>>5)][o] = attr[bt] . fc1_w[o] + fc1_b[o]
__global__ __launch_bounds__(256, 2) void stattn_fc2(
    const float* __restrict__ attr,   // [1024][512] (d_ws)
    const float* __restrict__ fc1_w,  // [256][512]
    const float* __restrict__ fc1_b,  // [256]
    float* __restrict__ out)          // [1024][256]
{
    __shared__ __align__(16) float at[32][516];
    const int tid = threadIdx.x;
    const int bm  = blockIdx.x;
    const int bn  = blockIdx.y;

    {
        const int row = tid >> 3;
        const int seg = tid & 7;
        const float* __restrict__ src = attr + (size_t)(bm * 32 + row) * 512 + seg * 64;
#pragma unroll
        for (int q = 0; q < 16; ++q)
            *reinterpret_cast<float4*>(&at[row][seg * 64 + q * 4]) =
                *reinterpret_cast<const float4*>(&src[q * 4]);
    }
    __syncthreads();

    const int tx = tid & 31;
    const int ty = tid >> 5;
    const int o  = bn * 32 + tx;
    const float* __restrict__ wr = fc1_w + (size_t)o * 512;
    float s0 = 0.f, s1 = 0.f, s2 = 0.f, s3 = 0.f;
#pragma unroll 4
    for (int kq = 0; kq < 128; ++kq) {
        const float4 w4 = *reinterpret_cast<const float4*>(&wr[kq * 4]);
        const float4 a0 = *reinterpret_cast<const float4*>(&at[ty * 4 + 0][kq * 4]);
        const float4 a1 = *reinterpret_cast<const float4*>(&at[ty * 4 + 1][kq * 4]);
        const float4 a2 = *reinterpret_cast<const float4*>(&at[ty * 4 + 2][kq * 4]);
        const float4 a3 = *reinterpret_cast<const float4*>(&at[ty * 4 + 3][kq * 4]);
        s0 += a0.x * w4.x + a0.y * w4.y + a0.z * w4.z + a0.w * w4.w;
        s1 += a1.x * w4.x + a1.y * w4.y + a1.z * w4.z + a1.w * w4.w;
        s2 += a2.x * w4.x + a2.y * w4.y + a2.z * w4.z + a2.w * w4.w;
        s3 += a3.x * w4.x + a3.y * w4.y + a3.z * w4.z + a3.w * w4.w;
    }
    const float fb = fc1_b[o];
    float sv0 = s0 + fb, sv1 = s1 + fb, sv2 = s2 + fb, sv3 = s3 + fb;
    {
        int btv = bm * 32 + ty * 4;
        out[((btv & 31) * 32 + (btv >> 5)) * 256 + o] = sv0; ++btv;
        out[((btv & 31) * 32 + (btv >> 5)) * 256 + o] = sv1; ++btv;
        out[((btv & 31) * 32 + (btv >> 5)) * 256 + o] = sv2; ++btv;
        out[((btv & 31) * 32 + (btv >> 5)) * 256 + o] = sv3;
    }
}

extern "C" void kernel_launch(void* const* d_in, const int* in_sizes, int n_in,
                              void* d_out, int out_size, void* d_ws, size_t ws_size,
                              hipStream_t stream) {
    const float* inp   = (const float*)d_in[0];
    const float* ue_w  = (const float*)d_in[1];
    const float* ue_b  = (const float*)d_in[2];
    const float* be    = (const float*)d_in[3];
    const float* w_w   = (const float*)d_in[4];
    // d_in[5] = w_b: unused (softmax invariant to constant shift)
    const float* fc1_w = (const float*)d_in[6];
    const float* fc1_b = (const float*)d_in[7];
    float* out = (float*)d_out;

    const size_t ATTR_BYTES = (size_t)1024 * 512 * 4;           // 2 MB
    const size_t PRE_BYTES  = (size_t)64 * 512 * 2 * 2;         // 128 KB
    const bool split = ws_size >= ATTR_BYTES;                   // confirmed R6
    const bool pre   = ws_size >= ATTR_BYTES + PRE_BYTES;

    if (split) {
        float* attr = (float*)d_ws;
        unsigned short* ue_hi =
            (unsigned short*)((char*)d_ws + ATTR_BYTES);
        unsigned short* ue_lo = ue_hi + 64 * 512;
        if (pre) {
            presplit_ue<<<32, 256, 0, stream>>>(ue_w, ue_hi, ue_lo);
            stattn_ea<0, 1><<<1024, 256, 0, stream>>>(
                inp, ue_w, ue_hi, ue_lo, ue_b, be, w_w, fc1_w, fc1_b, attr);
        } else {
            stattn_ea<0, 0><<<1024, 256, 0, stream>>>(
                inp, ue_w, ue_hi, ue_lo, ue_b, be, w_w, fc1_w, fc1_b, attr);
        }
        stattn_fc2<<<dim3(32, 8), 256, 0, stream>>>(attr, fc1_w, fc1_b, out);
    } else {
        stattn_ea<1, 0><<<1024, 256, 0, stream>>>(
            inp, ue_w, nullptr, nullptr, ue_b, be, w_w, fc1_w, fc1_b, out);
    }
}

// Round 14
// 98.583 us; speedup vs baseline: 1.0874x; 1.0479x over previous
//
#include <hip/hip_runtime.h>

// STAttn v13: B,T,N,D=32,32,64,512; H=64; OUT=256.
// R13 post-mortem: ws_size is exactly 2MB -> pre-split path never ran; R12/R13
// both executed the unpipelined fallback (identical counters, VGPR=32).
// R14: manual 4-slot NAMED-variable load pipeline applied to the in-kernel
// split path (no d_ws pre-split needed). Per slot: A 2xfloat4 + B 2xfloat4;
// consume slot i -> only its own (older) loads drain, slots i+1..i+3 stay in
// flight (VMEM FIFO works for us). Split both operands at consume time.
// Skeleton: 1024 blocks x 4 waves (nh,jh), zero-barrier k-loop, 2 block
// barriers, streamed pooling; attr -> d_ws (2MB exactly); fc2 kernel.
// MODE 1 fallback (ws < 2MB): fc fused in-block.

typedef __attribute__((ext_vector_type(8)))  short bf16x8;
typedef __attribute__((ext_vector_type(16))) float f32x16;

#define SCHEDB() __builtin_amdgcn_sched_barrier(0)

// one float -> bf16 hi (trunc) + lo (residual, trunc); alo*blo (~2^-16) dropped
#define SPL(f, i) do {                                                        \
    const unsigned u_ = __float_as_uint(f);                                   \
    h8[i] = (short)(u_ >> 16);                                                \
    const float hf_ = __uint_as_float(u_ & 0xFFFF0000u);                      \
    l8[i] = (short)(__float_as_uint((f) - hf_) >> 16);                        \
} while (0)

__device__ __forceinline__ void split8v(float4 va, float4 vb,
                                        bf16x8& h8, bf16x8& l8) {
    SPL(va.x, 0); SPL(va.y, 1); SPL(va.z, 2); SPL(va.w, 3);
    SPL(vb.x, 4); SPL(vb.y, 5); SPL(vb.z, 6); SPL(vb.w, 7);
}

template<int MODE>
__global__ __launch_bounds__(256, 2) void stattn_ea(
    const float* __restrict__ inp,    // [1024][64][512]
    const float* __restrict__ ue_w,   // [64][512]
    const float* __restrict__ ue_b,   // [64]
    const float* __restrict__ be,     // [64]
    const float* __restrict__ w_w,    // [64]
    const float* __restrict__ fc1_w,  // [256][512] (MODE 1 only)
    const float* __restrict__ fc1_b,  // [256]      (MODE 1 only)
    float* __restrict__ dst)          // MODE 0: attr; MODE 1: out
{
    __shared__ float ep_s[2][64];
    __shared__ float a_s[64];
    __shared__ __align__(16) float attr_s[512];  // MODE 1 only

    const int tid = threadIdx.x;
    const int wv  = tid >> 6;
    const int l   = tid & 63;
    const int l31 = l & 31;
    const int hi5 = l >> 5;
    const int nh  = wv >> 1;        // token half
    const int jh  = wv & 1;         // hidden half
    const int bt  = blockIdx.x;
    const float* __restrict__ xg = inp + (size_t)bt * (64 * 512);

    // ---- phase 1: 32x32 h-tile per wave, K=512, zero barriers,
    //      4-slot named-variable load pipeline (A and B from global) ----
    const float* __restrict__ arow = xg   + (nh * 32 + l31) * 512 + hi5 * 8;
    const float* __restrict__ brow = ue_w + (jh * 32 + l31) * 512 + hi5 * 8;

    f32x16 acc = {};

    float4 xa0, xb0, xa1, xb1, xa2, xb2, xa3, xb3;
    float4 wa0, wb0, wa1, wb1, wa2, wb2, wa3, wb3;

#define LOADS(i, ks) do {                                                     \
    xa##i = *reinterpret_cast<const float4*>(&arow[(ks) * 16]);               \
    xb##i = *reinterpret_cast<const float4*>(&arow[(ks) * 16 + 4]);           \
    wa##i = *reinterpret_cast<const float4*>(&brow[(ks) * 16]);               \
    wb##i = *reinterpret_cast<const float4*>(&brow[(ks) * 16 + 4]);           \
} while (0)
#define COMPS(i) do {                                                         \
    bf16x8 ah, al, bh, bl;                                                    \
    { bf16x8 &h8 = ah, &l8 = al; split8v(xa##i, xb##i, h8, l8); }             \
    { bf16x8 &h8 = bh, &l8 = bl; split8v(wa##i, wb##i, h8, l8); }             \
    acc = __builtin_amdgcn_mfma_f32_32x32x16_bf16(ah, bh, acc, 0, 0, 0);      \
    acc = __builtin_amdgcn_mfma_f32_32x32x16_bf16(al, bh, acc, 0, 0, 0);      \
    acc = __builtin_amdgcn_mfma_f32_32x32x16_bf16(ah, bl, acc, 0, 0, 0);      \
} while (0)

    LOADS(0, 0); LOADS(1, 1); LOADS(2, 2); LOADS(3, 3);
    SCHEDB();
#pragma unroll
    for (int ks = 0; ks < 32; ks += 4) {
        COMPS(0); if (ks + 4 < 32) LOADS(0, ks + 4); SCHEDB();
        COMPS(1); if (ks + 5 < 32) LOADS(1, ks + 5); SCHEDB();
        COMPS(2); if (ks + 6 < 32) LOADS(2, ks + 6); SCHEDB();
        COMPS(3); if (ks + 7 < 32) LOADS(3, ks + 7); SCHEDB();
    }
#undef LOADS
#undef COMPS

    // ---- phase 2: e = lrelu(h+bias)@w_w (w_b dropped: softmax shift-inv) ----
    // C/D layout (m74/m101): col j = l&31, row n = (r&3) + 8*(r>>2) + 4*(l>>5)
    {
        const int j = jh * 32 + l31;
        const float bias = ue_b[j] + be[j];
        const float ww   = w_w[j];
#pragma unroll
        for (int r = 0; r < 16; ++r) {
            float hv = acc[r] + bias;
            hv = hv > 0.f ? hv : 0.2f * hv;
            float p = hv * ww;
            p += __shfl_xor(p, 1);
            p += __shfl_xor(p, 2);
            p += __shfl_xor(p, 4);
            p += __shfl_xor(p, 8);
            p += __shfl_xor(p, 16);
            if (l31 == 0)
                ep_s[jh][nh * 32 + (r & 3) + 8 * (r >> 2) + 4 * hi5] = p;
        }
    }
    __syncthreads();

    // ---- softmax over 64 tokens (wave 0 computes & publishes) ----
    if (wv == 0) {
        const float v = ep_s[0][l] + ep_s[1][l];
        float mx = v;
#pragma unroll
        for (int off = 32; off >= 1; off >>= 1) mx = fmaxf(mx, __shfl_xor(mx, off));
        const float ex = expf(v - mx);
        float sm = ex;
#pragma unroll
        for (int off = 32; off >= 1; off >>= 1) sm += __shfl_xor(sm, off);
        a_s[l] = ex / sm;
    }
    __syncthreads();

    // ---- phase 3: pooling, streamed L2/L3-hot pass, no barriers ----
    {
        const int d0 = tid * 2;
        const float* __restrict__ xp = xg + d0;
        float sx = 0.f, sy = 0.f;
#pragma unroll 8
        for (int n = 0; n < 64; ++n) {
            const float an  = a_s[n];
            const float2 xv = *reinterpret_cast<const float2*>(&xp[n * 512]);
            sx = fmaf(an, xv.x, sx);
            sy = fmaf(an, xv.y, sy);
        }
        if (MODE == 0) {
            float2 o; o.x = sx; o.y = sy;
            *reinterpret_cast<float2*>(&dst[(size_t)bt * 512 + d0]) = o;
        } else {
            attr_s[d0]     = sx;
            attr_s[d0 + 1] = sy;
        }
    }

    if (MODE == 1) {
        __syncthreads();
        const int o = tid;
        const float* __restrict__ wr = fc1_w + o * 512;
        float s0 = 0.f, s1 = 0.f, s2 = 0.f, s3 = 0.f;
#pragma unroll 8
        for (int i = 0; i < 128; ++i) {
            const float4 w4 = *reinterpret_cast<const float4*>(&wr[i * 4]);
            const float4 a4 = *reinterpret_cast<const float4*>(&attr_s[i * 4]);
            s0 = fmaf(a4.x, w4.x, s0);
            s1 = fmaf(a4.y, w4.y, s1);
            s2 = fmaf(a4.z, w4.z, s2);
            s3 = fmaf(a4.w, w4.w, s3);
        }
        const int row = (bt & 31) * 32 + (bt >> 5);
        dst[row * 256 + o] = (s0 + s1) + (s2 + s3) + fc1_b[o];
    }
}

// fc GEMM: out[(bt&31)*32+(bt>>5)][o] = attr[bt] . fc1_w[o] + fc1_b[o]
__global__ __launch_bounds__(256, 2) void stattn_fc2(
    const float* __restrict__ attr,   // [1024][512] (d_ws)
    const float* __restrict__ fc1_w,  // [256][512]
    const float* __restrict__ fc1_b,  // [256]
    float* __restrict__ out)          // [1024][256]
{
    __shared__ __align__(16) float at[32][516];
    const int tid = threadIdx.x;
    const int bm  = blockIdx.x;
    const int bn  = blockIdx.y;

    {
        const int row = tid >> 3;
        const int seg = tid & 7;
        const float* __restrict__ src = attr + (size_t)(bm * 32 + row) * 512 + seg * 64;
#pragma unroll
        for (int q = 0; q < 16; ++q)
            *reinterpret_cast<float4*>(&at[row][seg * 64 + q * 4]) =
                *reinterpret_cast<const float4*>(&src[q * 4]);
    }
    __syncthreads();

    const int tx = tid & 31;
    const int ty = tid >> 5;
    const int o  = bn * 32 + tx;
    const float* __restrict__ wr = fc1_w + (size_t)o * 512;
    float s0 = 0.f, s1 = 0.f, s2 = 0.f, s3 = 0.f;
#pragma unroll 4
    for (int kq = 0; kq < 128; ++kq) {
        const float4 w4 = *reinterpret_cast<const float4*>(&wr[kq * 4]);
        const float4 a0 = *reinterpret_cast<const float4*>(&at[ty * 4 + 0][kq * 4]);
        const float4 a1 = *reinterpret_cast<const float4*>(&at[ty * 4 + 1][kq * 4]);
        const float4 a2 = *reinterpret_cast<const float4*>(&at[ty * 4 + 2][kq * 4]);
        const float4 a3 = *reinterpret_cast<const float4*>(&at[ty * 4 + 3][kq * 4]);
        s0 += a0.x * w4.x + a0.y * w4.y + a0.z * w4.z + a0.w * w4.w;
        s1 += a1.x * w4.x + a1.y * w4.y + a1.z * w4.z + a1.w * w4.w;
        s2 += a2.x * w4.x + a2.y * w4.y + a2.z * w4.z + a2.w * w4.w;
        s3 += a3.x * w4.x + a3.y * w4.y + a3.z * w4.z + a3.w * w4.w;
    }
    const float fb = fc1_b[o];
    float sv0 = s0 + fb, sv1 = s1 + fb, sv2 = s2 + fb, sv3 = s3 + fb;
    {
        int btv = bm * 32 + ty * 4;
        out[((btv & 31) * 32 + (btv >> 5)) * 256 + o] = sv0; ++btv;
        out[((btv & 31) * 32 + (btv >> 5)) * 256 + o] = sv1; ++btv;
        out[((btv & 31) * 32 + (btv >> 5)) * 256 + o] = sv2; ++btv;
        out[((btv & 31) * 32 + (btv >> 5)) * 256 + o] = sv3;
    }
}

extern "C" void kernel_launch(void* const* d_in, const int* in_sizes, int n_in,
                              void* d_out, int out_size, void* d_ws, size_t ws_size,
                              hipStream_t stream) {
    const float* inp   = (const float*)d_in[0];
    const float* ue_w  = (const float*)d_in[1];
    const float* ue_b  = (const float*)d_in[2];
    const float* be    = (const float*)d_in[3];
    const float* w_w   = (const float*)d_in[4];
    // d_in[5] = w_b: unused (softmax invariant to constant shift)
    const float* fc1_w = (const float*)d_in[6];
    const float* fc1_b = (const float*)d_in[7];
    float* out = (float*)d_out;

    const size_t ATTR_BYTES = (size_t)1024 * 512 * 4;  // 2 MB == ws_size (R13)
    const bool split = ws_size >= ATTR_BYTES;

    if (split) {
        float* attr = (float*)d_ws;
        stattn_ea<0><<<1024, 256, 0, stream>>>(inp, ue_w, ue_b, be, w_w,
                                               fc1_w, fc1_b, attr);
        stattn_fc2<<<dim3(32, 8), 256, 0, stream>>>(attr, fc1_w, fc1_b, out);
    } else {
        stattn_ea<1><<<1024, 256, 0, stream>>>(inp, ue_w, ue_b, be, w_w,
                                               fc1_w, fc1_b, out);
    }
}